// Round 2
// baseline (127.731 us; speedup 1.0000x reference)
//
#include <hip/hip_runtime.h>
#include <math.h>

// Problem constants (reference: BATCH=4096, DIM=512, sigma = s*I).
#define NB 4096
#define ND 512
#define TILE 128
#define BK 32
#define NT (NB / TILE)             // 32 tile-rows
#define NBLK (NT * (NT + 1) / 2)   // 528 lower-triangular tiles

typedef __bf16 bf16x8 __attribute__((ext_vector_type(8)));
typedef float floatx4 __attribute__((ext_vector_type(4)));

__device__ inline void async_load16(const void* g, void* l) {
    __builtin_amdgcn_global_load_lds((const __attribute__((address_space(1))) void*)g,
                                     (__attribute__((address_space(3))) void*)l, 16, 0, 0);
}

// Kernel 1: cast mu -> bf16 (one wave per row), hq[i] = 0.5*sum(bf16(x)^2),
// zero sumexp + completion counter (ws is re-poisoned before every launch).
__global__ __launch_bounds__(256) void prep_kernel(const float* __restrict__ mu,
                                                   __bf16* __restrict__ mubf,
                                                   float* __restrict__ hq,
                                                   float* __restrict__ sumexp,
                                                   unsigned* __restrict__ counter) {
    const int t = threadIdx.x;
    const int wave = t >> 6, lane = t & 63;
    const int row = blockIdx.x * 4 + wave;
    const float4* src = (const float4*)(mu + (size_t)row * ND) + lane * 2;
    const float4 v0 = src[0], v1 = src[1];
    bf16x8 pack;
    pack[0] = (__bf16)v0.x; pack[1] = (__bf16)v0.y;
    pack[2] = (__bf16)v0.z; pack[3] = (__bf16)v0.w;
    pack[4] = (__bf16)v1.x; pack[5] = (__bf16)v1.y;
    pack[6] = (__bf16)v1.z; pack[7] = (__bf16)v1.w;
    ((bf16x8*)(mubf + (size_t)row * ND))[lane] = pack;
    float sq = 0.0f;
    #pragma unroll
    for (int e = 0; e < 8; e++) { float f = (float)pack[e]; sq += f * f; }
    #pragma unroll
    for (int off = 32; off > 0; off >>= 1) sq += __shfl_down(sq, off, 64);
    if (lane == 0) {
        hq[row] = 0.5f * sq;
        sumexp[row] = 0.0f;
    }
    if (blockIdx.x == 0 && t == 0) *counter = 0u;
}

// Kernel 2: lower-triangular tiles of the symmetric Gram; fused exp +
// row-sum AND col-sum scatter (symmetry) + last-block finalize.
// expo[i,j] = (G_ij - hq_i - hq_j)/s <= ~0, max on diagonal = 0, so a
// plain sum of exps never overflows — no online max needed.
__global__ __launch_bounds__(256) void gram_lse_kernel(const __bf16* __restrict__ mubf,
                                                       const float* __restrict__ hq,
                                                       const float* __restrict__ sigma,
                                                       float* __restrict__ sumexp,
                                                       unsigned* __restrict__ counter,
                                                       float* __restrict__ out) {
    __shared__ alignas(16) __bf16 As[TILE * BK];   // [row][k], k-stride 32
    __shared__ alignas(16) __bf16 Bs[TILE * BK];

    // Decode linear block id -> lower-triangular (ti >= tj).
    int b = blockIdx.x;
    int ti = (int)((sqrt(8.0 * (double)b + 1.0) - 1.0) * 0.5);
    while ((ti + 1) * (ti + 2) / 2 <= b) ti++;
    while (ti * (ti + 1) / 2 > b) ti--;
    const int tj = b - ti * (ti + 1) / 2;
    const bool isDiag = (ti == tj);
    const int row0 = ti * TILE;
    const int col0 = tj * TILE;

    const int t = threadIdx.x;
    const int wave = t >> 6;
    const int lane = t & 63;
    const int r16 = lane & 15;
    const int quad = lane >> 4;
    const int rw = (wave >> 1) * 64;   // wave's row offset within tile
    const int cw = (wave & 1) * 64;    // wave's col offset within tile

    // Staging: thread t moves 16B: row (t>>2), k elems [(t&3)*8, +8)
    const int srow = t >> 2;
    const int skoff = (t & 3) * 8;
    const __bf16* gA0 = mubf + (size_t)(row0 + srow) * ND + skoff;
    const __bf16* gA1 = gA0 + (size_t)64 * ND;
    const __bf16* gB0 = mubf + (size_t)(col0 + srow) * ND + skoff;
    const __bf16* gB1 = gB0 + (size_t)64 * ND;
    __bf16* lA0 = &As[t * 8];
    __bf16* lA1 = &As[2048 + t * 8];
    __bf16* lB0 = &Bs[t * 8];
    __bf16* lB1 = &Bs[2048 + t * 8];
    const __bf16* Bsrc = isDiag ? As : Bs;   // diagonal tile: B == A

    floatx4 acc[4][4];
    #pragma unroll
    for (int i = 0; i < 4; i++)
        #pragma unroll
        for (int j = 0; j < 4; j++) {
            floatx4 z = {0.f, 0.f, 0.f, 0.f};
            acc[i][j] = z;
        }

    for (int kk = 0; kk < ND; kk += BK) {
        __syncthreads();                       // protect LDS from prior reads
        async_load16(gA0 + kk, lA0);
        async_load16(gA1 + kk, lA1);
        if (!isDiag) {
            async_load16(gB0 + kk, lB0);
            async_load16(gB1 + kk, lB1);
        }
        __syncthreads();                       // drains vmcnt before barrier

        bf16x8 a[4], bb[4];
        #pragma unroll
        for (int i = 0; i < 4; i++)
            a[i] = *(const bf16x8*)&As[(rw + i * 16 + r16) * BK + quad * 8];
        #pragma unroll
        for (int j = 0; j < 4; j++)
            bb[j] = *(const bf16x8*)&Bsrc[(cw + j * 16 + r16) * BK + quad * 8];
        #pragma unroll
        for (int i = 0; i < 4; i++)
            #pragma unroll
            for (int j = 0; j < 4; j++)
                acc[i][j] = __builtin_amdgcn_mfma_f32_16x16x32_bf16(a[i], bb[j], acc[i][j], 0, 0, 0);
    }

    // Epilogue. C/D layout (m89-verified): col = lane&15, row = quad*4 + reg.
    const float inv_s = 1.0f / sigma[0];
    float hqc[4];
    #pragma unroll
    for (int j = 0; j < 4; j++) hqc[j] = hq[col0 + cw + j * 16 + r16];

    float cs[4] = {0.f, 0.f, 0.f, 0.f};       // per-lane column partials
    #pragma unroll
    for (int i = 0; i < 4; i++) {
        #pragma unroll
        for (int r = 0; r < 4; r++) {
            const int row = row0 + rw + i * 16 + quad * 4 + r;
            const float hr = hq[row];
            float rs = 0.0f;
            #pragma unroll
            for (int j = 0; j < 4; j++) {
                const float v = __expf((acc[i][j][r] - hr - hqc[j]) * inv_s);
                rs += v;
                cs[j] += v;
            }
            rs += __shfl_xor(rs, 1, 64);
            rs += __shfl_xor(rs, 2, 64);
            rs += __shfl_xor(rs, 4, 64);
            rs += __shfl_xor(rs, 8, 64);
            if (r16 == 0) atomicAdd(&sumexp[row], rs);
        }
    }
    if (!isDiag) {
        // Column sums -> rows of the tj tile (symmetry). Reduce across quads.
        #pragma unroll
        for (int j = 0; j < 4; j++) {
            float c = cs[j];
            c += __shfl_xor(c, 16, 64);
            c += __shfl_xor(c, 32, 64);
            if (quad == 0) atomicAdd(&sumexp[col0 + cw + j * 16 + r16], c);
        }
    }

    // Last block finalizes: entropy = D/2 + ln B + (D/2)ln(2*pi*s) - mean log sumexp
    __threadfence();
    __syncthreads();
    __shared__ unsigned done;
    if (t == 0)
        done = __hip_atomic_fetch_add(counter, 1u, __ATOMIC_ACQ_REL, __HIP_MEMORY_SCOPE_AGENT);
    __syncthreads();
    if (done == NBLK - 1) {
        float local = 0.0f;
        for (int i = t; i < NB; i += 256)
            local += logf(__hip_atomic_load(&sumexp[i], __ATOMIC_RELAXED, __HIP_MEMORY_SCOPE_AGENT));
        #pragma unroll
        for (int off = 32; off > 0; off >>= 1) local += __shfl_down(local, off, 64);
        __shared__ float fred[4];
        if ((t & 63) == 0) fred[t >> 6] = local;
        __syncthreads();
        if (t == 0) {
            const double tot = (double)fred[0] + fred[1] + fred[2] + fred[3];
            const double s = (double)sigma[0];
            const double ent = (double)(ND / 2)
                             + log((double)NB)
                             + (double)(ND / 2) * log(2.0 * M_PI * s)
                             - tot / (double)NB;
            out[0] = (float)ent;
            out[1] = (float)ent;
        }
    }
}

extern "C" void kernel_launch(void* const* d_in, const int* in_sizes, int n_in,
                              void* d_out, int out_size, void* d_ws, size_t ws_size,
                              hipStream_t stream) {
    (void)in_sizes; (void)n_in; (void)out_size; (void)ws_size;
    const float* codewords = (const float*)d_in[1];  // d_in[0] = info (unused)
    const float* sigma     = (const float*)d_in[2];
    float* out = (float*)d_out;

    char* ws = (char*)d_ws;
    __bf16* mubf   = (__bf16*)ws;                                  // 4 MB
    float*  hq     = (float*)(ws + (size_t)NB * ND * 2);           // 16 KB
    float*  sumexp = hq + NB;                                      // 16 KB
    unsigned* counter = (unsigned*)(sumexp + NB);                  // 4 B

    prep_kernel<<<NB / 4, 256, 0, stream>>>(codewords, mubf, hq, sumexp, counter);
    gram_lse_kernel<<<NBLK, 256, 0, stream>>>(mubf, hq, sigma, sumexp, counter, out);
}